// Round 7
// baseline (25849.844 us; speedup 1.0000x reference)
//
#include <hip/hip_runtime.h>

// HighwayLayerDiscrete: 256-step recurrent highway net, batch 64, units 1024.
// Reference per step: p0 h=lrelu(y@w_y+xe@w_x+b_in); p1/p2 h=lrelu(h@w_h+b_h);
// p3 y += h@w_out + b_out; out[:,t,:]=y.
//
// R14 = R13 phase mechanics (proven 6.23 ms) with the ALGEBRA refolded from
// 4 exchange phases/step to 3:  track z_t := y_t @ w_y as private state.
//   z_{t+1} = z_t + h2@w_ow + b_ow   (w_ow = w_out@w_y, b_ow = b_out@w_y,
//                                     precomputed once in a prologue GEMM)
//   h0_{t+1} = lrelu(z_{t+1} + xp[t+1])   -- ELEMENTWISE, WG-private
//   y_{t+1} = y_t + h2@w_out + b_out      -- y is 1 reg/thread, never staged
// Pipeline/step: A: stage h0 -> h1=lrelu(h0@wh0+bh0)
//               B: stage h1 -> h2=lrelu(h1@wh1+bh1)
//               C: stage h2 -> pass1 ydelta=h2@w_out (y+=..., out[t]=y)
//                              pass2 zdelta=h2@w_ow  (z+=..., store h0' slot)
// Exchanges/step 4->3; y-slot traffic gone. Phase C reuses the SAME staged
// a_s for both passes; w_ow panel loaded mid-phase (hidden under finalize-y).
// Carried R13 wins: per-producer flag stores + coalesced 32-lane poll
// (bounded 2^20); finalize operands prefetched at phase start; out-store
// deferred past flag post. Carried invariants: 256 coop blocks x 512 thr
// (R4); no cross-WG split-K (R2/R3); no fences (R1); sc1/LLC only (R9:
// sc0 deadlocks); release = waitcnt0+barrier+flag store; acquire = poll +
// barrier + clobber; LDS skew injective (R5); red2 de-aliased (R8-ok).
// Numerics: h2@(w_out@w_y) reassociation ~1e-6 rel/step, same order as the
// existing split-K reassociation.

constexpr int B = 64, T = 256, U = 1024, E = 512;
constexpr int BU = B * U;     // 65536
constexpr int APITCH = 1156;  // A-row pitch (1024 + 36-skew; ==4 mod 8)

#define LRELU(v) ((v) > 0.f ? (v) : 0.2f * (v))

using f4 = float __attribute__((ext_vector_type(4)));

__device__ __forceinline__ unsigned long long llc_load64(const float* p) {
  return __hip_atomic_load((const unsigned long long*)p, __ATOMIC_RELAXED,
                           __HIP_MEMORY_SCOPE_AGENT);
}
__device__ __forceinline__ void llc_store(float* p, float v) {
  __hip_atomic_store(p, v, __ATOMIC_RELAXED, __HIP_MEMORY_SCOPE_AGENT);
}
__device__ __forceinline__ unsigned llc_flag(const unsigned* p) {
  return __hip_atomic_load(p, __ATOMIC_RELAXED, __HIP_MEMORY_SCOPE_AGENT);
}
__device__ __forceinline__ void llc_flag_store(unsigned* p, unsigned v) {
  __hip_atomic_store(p, v, __ATOMIC_RELAXED, __HIP_MEMORY_SCOPE_AGENT);
}

// -------- init: zero flags and the k_vecs atomic accumulators --------
__global__ void k_init(unsigned* __restrict__ flags, float* __restrict__ z0,
                       float* __restrict__ b_ow) {
  int i = blockIdx.x * 256 + threadIdx.x;  // grid 4 -> 1024
  if (i < 1024) {
    flags[i] = 0u;
    z0[i] = 0.f;
    b_ow[i] = 0.f;
  }
}

// ------- xproj[t*64+n][u] = emb[x[n][t]] @ w_x + b_in (R2/R3-proven) -------
__global__ __launch_bounds__(256) void k_xproj(
    const int* __restrict__ x, const float* __restrict__ emb,
    const float* __restrict__ w_x, const float* __restrict__ b_in,
    float* __restrict__ xp) {
  __shared__ float a_s[64][36];
  __shared__ float w_s[32][64];
  __shared__ int idxs[64];
  const int tid = threadIdx.x;
  const int m0 = blockIdx.x * 64;
  const int c0 = blockIdx.y * 64;
  if (tid < 64) {
    int m = m0 + tid;
    idxs[tid] = x[(m & 63) * T + (m >> 6)];  // x[n][t], row m = t*64+n
  }
  __syncthreads();
  const int rq = tid >> 4, cq = tid & 15;
  float acc[4][4] = {};
  for (int k0 = 0; k0 < E; k0 += 32) {
#pragma unroll
    for (int rep = 0; rep < 8; ++rep) {
      int e = rep * 256 + tid;
      int r = e >> 5, k = e & 31;
      a_s[r][k] = emb[(size_t)idxs[r] * E + k0 + k];
    }
#pragma unroll
    for (int rep = 0; rep < 2; ++rep) {
      int e = rep * 256 + tid;
      int kr = e >> 4, q = e & 15;
      *(float4*)&w_s[kr][4 * q] =
          *(const float4*)(w_x + (size_t)(k0 + kr) * U + c0 + 4 * q);
    }
    __syncthreads();
#pragma unroll
    for (int kc = 0; kc < 32; kc += 4) {
      float4 a4[4], w4[4];
#pragma unroll
      for (int i = 0; i < 4; ++i) a4[i] = *(const float4*)&a_s[4 * rq + i][kc];
#pragma unroll
      for (int kk = 0; kk < 4; ++kk)
        w4[kk] = *(const float4*)&w_s[kc + kk][4 * cq];
#pragma unroll
      for (int i = 0; i < 4; ++i) {
        const float av[4] = {a4[i].x, a4[i].y, a4[i].z, a4[i].w};
#pragma unroll
        for (int kk = 0; kk < 4; ++kk) {
          acc[i][0] += av[kk] * w4[kk].x;
          acc[i][1] += av[kk] * w4[kk].y;
          acc[i][2] += av[kk] * w4[kk].z;
          acc[i][3] += av[kk] * w4[kk].w;
        }
      }
    }
    __syncthreads();
  }
  const float4 bb = *(const float4*)(b_in + c0 + 4 * cq);
  const float bv[4] = {bb.x, bb.y, bb.z, bb.w};
#pragma unroll
  for (int i = 0; i < 4; ++i) {
    float4 o;
    o.x = acc[i][0] + bv[0];
    o.y = acc[i][1] + bv[1];
    o.z = acc[i][2] + bv[2];
    o.w = acc[i][3] + bv[3];
    *(float4*)(xp + (size_t)(m0 + 4 * rq + i) * U + c0 + 4 * cq) = o;
  }
}

// -------- w_ow[k][u] = sum_j w_out[k][j] * w_y[j][u]  (same tile GEMM) -----
__global__ __launch_bounds__(256) void k_wcat(const float* __restrict__ wo,
                                              const float* __restrict__ wy,
                                              float* __restrict__ wow) {
  __shared__ float a_s[64][36];
  __shared__ float w_s[32][64];
  const int tid = threadIdx.x;
  const int m0 = blockIdx.x * 64;
  const int c0 = blockIdx.y * 64;
  const int rq = tid >> 4, cq = tid & 15;
  float acc[4][4] = {};
  for (int k0 = 0; k0 < U; k0 += 32) {
#pragma unroll
    for (int rep = 0; rep < 8; ++rep) {
      int e = rep * 256 + tid;
      int r = e >> 5, k = e & 31;
      a_s[r][k] = wo[(size_t)(m0 + r) * U + k0 + k];
    }
#pragma unroll
    for (int rep = 0; rep < 2; ++rep) {
      int e = rep * 256 + tid;
      int kr = e >> 4, q = e & 15;
      *(float4*)&w_s[kr][4 * q] =
          *(const float4*)(wy + (size_t)(k0 + kr) * U + c0 + 4 * q);
    }
    __syncthreads();
#pragma unroll
    for (int kc = 0; kc < 32; kc += 4) {
      float4 a4[4], w4[4];
#pragma unroll
      for (int i = 0; i < 4; ++i) a4[i] = *(const float4*)&a_s[4 * rq + i][kc];
#pragma unroll
      for (int kk = 0; kk < 4; ++kk)
        w4[kk] = *(const float4*)&w_s[kc + kk][4 * cq];
#pragma unroll
      for (int i = 0; i < 4; ++i) {
        const float av[4] = {a4[i].x, a4[i].y, a4[i].z, a4[i].w};
#pragma unroll
        for (int kk = 0; kk < 4; ++kk) {
          acc[i][0] += av[kk] * w4[kk].x;
          acc[i][1] += av[kk] * w4[kk].y;
          acc[i][2] += av[kk] * w4[kk].z;
          acc[i][3] += av[kk] * w4[kk].w;
        }
      }
    }
    __syncthreads();
  }
#pragma unroll
  for (int i = 0; i < 4; ++i) {
    float4 o = {acc[i][0], acc[i][1], acc[i][2], acc[i][3]};
    *(float4*)(wow + (size_t)(m0 + 4 * rq + i) * U + c0 + 4 * cq) = o;
  }
}

// -------- z0[u] = h0 @ w_y[:,u];  b_ow[u] = b_out @ w_y[:,u] --------
__global__ void k_vecs(const float* __restrict__ h0,
                       const float* __restrict__ b_out,
                       const float* __restrict__ w_y, float* __restrict__ z0,
                       float* __restrict__ b_ow) {
  const int u = (blockIdx.x & 3) * 256 + threadIdx.x;
  const int kb = blockIdx.x >> 2;  // 8 k-blocks x 128
  float a0 = 0.f, a1 = 0.f;
  for (int k = kb * 128; k < kb * 128 + 128; ++k) {
    float w = w_y[(size_t)k * U + u];
    a0 += h0[k] * w;
    a1 += b_out[k] * w;
  }
  atomicAdd(&z0[u], a0);
  atomicAdd(&b_ow[u], a1);
}

// -------- slot1[n][u] = h0_0 = lrelu(z0[u] + xp[0][n][u]) --------
__global__ void k_fill(const float* __restrict__ z0,
                       const float* __restrict__ xp,
                       float* __restrict__ slot1) {
  int i = blockIdx.x * 256 + threadIdx.x;  // grid 256 -> 65536
  float v = z0[i & (U - 1)] + xp[i];
  slot1[i] = LRELU(v);
}

// ---------------- sequential pipeline: 768 phases ----------------
// 256 WGs = 8 rg x 32 cg. Thread (s,ri,ci): K-slice [32s,32s+32), rows
// [4ri,4ri+4) of 8, cols [4ci,4ci+4) of 32. Partials -> red2[s][out] pitch
// 264 (de-aliased). Phase Q = 3t+ph: ph0 A(w_h0), ph1 B(w_h1), ph2 C(w_out
// pass1 -> y, w_ow pass2 -> z, private h0' store).
__global__ __launch_bounds__(512, 2) void k_seq(
    const float* __restrict__ xp, const float* __restrict__ w_h,
    const float* __restrict__ b_h, const float* __restrict__ w_out,
    const float* __restrict__ w_ow, const float* __restrict__ b_out,
    const float* __restrict__ b_ow, const float* __restrict__ z0,
    const float* __restrict__ h0, float* __restrict__ out,
    float* __restrict__ slots, unsigned* __restrict__ flags) {
  __shared__ float a_s[8 * APITCH];   // 9248 floats
  __shared__ float red2[32 * 264];    // 8448 floats (de-aliased)
  const int tid = threadIdx.x;
  const int cg = blockIdx.x & 31, rg = blockIdx.x >> 5;
  const int l = tid & 63;
  const int ci = l & 7, ri = (l >> 3) & 1;
  const int s = (tid >> 6) * 4 + ((l >> 4) & 3);
  const int cb = 4 * ci, r0 = 4 * ri, k0 = 32 * s;
  unsigned* const myflag = &flags[rg * 32 + cg];
  const unsigned* const pollf = &flags[rg * 32 + (l & 31)];
  // finalize coordinates + loop-invariant operands (valid for all tid)
  const int frow = 8 * rg + (tid >> 5);
  const int fu = 32 * cg + (tid & 31);
  const size_t fyi = (size_t)frow * U + fu;
  const float bh0r = b_h[fu], bh1r = b_h[U + fu];
  const float bor = b_out[fu], bowr = b_ow[fu];
  float y_reg = h0[fu];  // y_0 = broadcast(h0)
  float z_reg = z0[fu];  // z_0 = broadcast(h0 @ w_y)

  // W panel base for phase type 0/1/2 (C pass1 = w_out; pass2 loaded inline)
  auto wbase = [&](int pht) -> const float* {
    const float* Wsrc = (pht == 0)   ? w_h
                        : (pht == 1) ? (w_h + (size_t)U * U)
                                     : w_out;
    return Wsrc + (size_t)k0 * U + 32 * cg + cb;
  };
  f4 wreg[32];
  {
    const float* wp = wbase(0);
#pragma unroll
    for (int j = 0; j < 32; ++j) wreg[j] = *(const f4*)(wp + (size_t)j * U);
  }

  int t = 0, ph = 0;
  for (int Q = 0; Q < 3 * T; ++Q) {
    const float* Asrc =
        slots + (size_t)((Q + 1) & 1) * BU + (size_t)(8 * rg) * U;
    float* slotw = slots + (size_t)(Q & 1) * BU;
    // ---- 0. xp prefetch for C (next timestep's xproj; hides under poll) ---
    float xpre = 0.f;
    if (ph == 2 && tid < 256) {
      const int tn = (t < T - 1) ? t + 1 : t;  // clamped; unused at t=T-1
      xpre = xp[((size_t)tn * B + frow) * U + fu];
    }
    // ---- 1. acquire: wave0's 32 lanes, one 128B flag read, bounded ----
    if (Q > 0) {
      if (tid < 64) {
        const unsigned tg = (unsigned)Q;
        for (int it = 0; it < (1 << 20); ++it) {
          unsigned f = llc_flag(pollf);
          if (__all((int)(f >= tg))) break;
          __builtin_amdgcn_s_sleep(1);
        }
      }
      __syncthreads();
      asm volatile("" ::: "memory");
    }
    // ---- 2. stage A: 8 rows x 1024, 8B sc1 loads -> b128 LDS write ----
#pragma unroll
    for (int rep = 0; rep < 4; ++rep) {
      int idx4 = 512 * rep + tid;
      int row = idx4 >> 8, kq = idx4 & 255, k = 4 * kq;
      const float* pa = Asrc + (size_t)row * U + k;
      unsigned long long v0 = llc_load64(pa);
      unsigned long long v1 = llc_load64(pa + 2);
      f4 v;
      ((unsigned long long*)&v)[0] = v0;
      ((unsigned long long*)&v)[1] = v1;
      *(f4*)&a_s[row * APITCH + 36 * (k >> 5) + (k & 31)] = v;
    }
    __syncthreads();
    // ---- 3. pass-1 GEMM: A from LDS, W from registers ----
    f4 acc[4];
#pragma unroll
    for (int i = 0; i < 4; ++i) acc[i] = (f4){0.f, 0.f, 0.f, 0.f};
    const int abase = r0 * APITCH + 36 * s;
#pragma unroll
    for (int q = 0; q < 8; ++q) {
      const int ai = abase + 4 * q;
      f4 a0 = *(const f4*)&a_s[ai];
      f4 a1 = *(const f4*)&a_s[ai + APITCH];
      f4 a2 = *(const f4*)&a_s[ai + 2 * APITCH];
      f4 a3 = *(const f4*)&a_s[ai + 3 * APITCH];
      const f4 w0 = wreg[4 * q], w1 = wreg[4 * q + 1];
      const f4 w2 = wreg[4 * q + 2], w3 = wreg[4 * q + 3];
      acc[0] += a0.x * w0 + a0.y * w1 + a0.z * w2 + a0.w * w3;
      acc[1] += a1.x * w0 + a1.y * w1 + a1.z * w2 + a1.w * w3;
      acc[2] += a2.x * w0 + a2.y * w1 + a2.z * w2 + a2.w * w3;
      acc[3] += a3.x * w0 + a3.y * w1 + a3.z * w2 + a3.w * w3;
    }
    if (ph == 2) {
      // mid-C reload: w_ow panel for pass-2 (latency hides under red/finalize)
      const float* wp = w_ow + (size_t)k0 * U + 32 * cg + cb;
#pragma unroll
      for (int j = 0; j < 32; ++j) wreg[j] = *(const f4*)(wp + (size_t)j * U);
    }
    // ---- 4. write partials (de-aliased: no pre-barrier) ----
#pragma unroll
    for (int i = 0; i < 4; ++i)
      *(f4*)&red2[s * 264 + (r0 + i) * 32 + cb] = acc[i];
    __syncthreads();
    // ---- 5. finalize ----
    if (ph < 2) {
      if (tid < 256) {
        float sum = 0.f;
#pragma unroll
        for (int z = 0; z < 32; ++z) sum += red2[z * 264 + tid];
        float v = sum + (ph ? bh1r : bh0r);
        llc_store(slotw + fyi, LRELU(v));
      }
    } else {
      // C: finalize-y (private), then pass-2 GEMM with w_ow, finalize-z
      if (tid < 256) {
        float ysum = 0.f;
#pragma unroll
        for (int z = 0; z < 32; ++z) ysum += red2[z * 264 + tid];
        y_reg += ysum + bor;  // out-store deferred past flag post
      }
      __syncthreads();  // red2-y reads done -> safe to overwrite
      f4 accz[4];
#pragma unroll
      for (int i = 0; i < 4; ++i) accz[i] = (f4){0.f, 0.f, 0.f, 0.f};
#pragma unroll
      for (int q = 0; q < 8; ++q) {
        const int ai = abase + 4 * q;
        f4 a0 = *(const f4*)&a_s[ai];
        f4 a1 = *(const f4*)&a_s[ai + APITCH];
        f4 a2 = *(const f4*)&a_s[ai + 2 * APITCH];
        f4 a3 = *(const f4*)&a_s[ai + 3 * APITCH];
        const f4 w0 = wreg[4 * q], w1 = wreg[4 * q + 1];
        const f4 w2 = wreg[4 * q + 2], w3 = wreg[4 * q + 3];
        accz[0] += a0.x * w0 + a0.y * w1 + a0.z * w2 + a0.w * w3;
        accz[1] += a1.x * w0 + a1.y * w1 + a1.z * w2 + a1.w * w3;
        accz[2] += a2.x * w0 + a2.y * w1 + a2.z * w2 + a2.w * w3;
        accz[3] += a3.x * w0 + a3.y * w1 + a3.z * w2 + a3.w * w3;
      }
#pragma unroll
      for (int i = 0; i < 4; ++i)
        *(f4*)&red2[s * 264 + (r0 + i) * 32 + cb] = accz[i];
      __syncthreads();
      if (tid < 256) {
        float zsum = 0.f;
#pragma unroll
        for (int z = 0; z < 32; ++z) zsum += red2[z * 264 + tid];
        z_reg += zsum + bowr;
        if (t < T - 1) {  // h0' for the next timestep's phase A
          float v = z_reg + xpre;
          llc_store(slotw + fyi, LRELU(v));
        }
      }
    }
    // ---- 6. drain: exchange stores at LLC before the flag post ----
    asm volatile("" ::: "memory");
    __builtin_amdgcn_s_waitcnt(0);
    __syncthreads();
    // ---- 7. W prefetch for Q+1 (overlaps post + poll + next stage) ----
    if (Q < 3 * T - 1) {
      const float* wp = wbase(ph == 2 ? 0 : ph + 1);
#pragma unroll
      for (int j = 0; j < 32; ++j) wreg[j] = *(const f4*)(wp + (size_t)j * U);
    }
    // ---- 8. release: per-producer flag store ----
    if (tid == 0) llc_flag_store(myflag, (unsigned)(Q + 1));
    // ---- 9. deferred out-store (off the flag critical path) ----
    if (ph == 2 && tid < 256) out[((size_t)frow * T + t) * U + fu] = y_reg;
    if (++ph == 3) {
      ph = 0;
      ++t;
    }
  }
}

extern "C" void kernel_launch(void* const* d_in, const int* in_sizes, int n_in,
                              void* d_out, int out_size, void* d_ws,
                              size_t ws_size, hipStream_t stream) {
  const int* x = (const int*)d_in[0];
  const float* emb = (const float*)d_in[1];
  const float* w_y = (const float*)d_in[2];
  const float* w_x = (const float*)d_in[3];
  const float* b_in = (const float*)d_in[4];
  const float* w_h = (const float*)d_in[5];
  const float* b_h = (const float*)d_in[6];
  const float* w_out = (const float*)d_in[7];
  const float* b_out = (const float*)d_in[8];
  const float* h0 = (const float*)d_in[9];
  float* out = (float*)d_out;

  // workspace (floats): xproj | slots[2] | flags(1024u) | z0 | b_ow | w_ow
  float* ws = (float*)d_ws;
  float* xpb = ws;                           // T*B*U = 16,777,216
  float* slots = xpb + (size_t)T * B * U;    // 2*BU = 131,072
  unsigned* flags = (unsigned*)(slots + 2 * (size_t)BU);  // 1024 uints
  float* z0 = (float*)(flags + 1024);        // 1024
  float* b_ow = z0 + 1024;                   // 1024
  float* w_ow = b_ow + 1024;                 // U*U = 1,048,576 (4 MB)

  k_init<<<4, 256, 0, stream>>>(flags, z0, b_ow);
  dim3 g1(256, 16);
  k_xproj<<<g1, 256, 0, stream>>>(x, emb, w_x, b_in, xpb);
  dim3 g2(16, 16);
  k_wcat<<<g2, 256, 0, stream>>>(w_out, w_y, w_ow);
  k_vecs<<<32, 256, 0, stream>>>(h0, b_out, w_y, z0, b_ow);
  k_fill<<<256, 256, 0, stream>>>(z0, xpb, slots + (size_t)BU);

  void* args[] = {&xpb, &w_h, &b_h,  &w_out, &w_ow,  &b_out,
                  &b_ow, &z0,  &h0,   &out,   &slots, &flags};
  hipLaunchCooperativeKernel((void*)k_seq, dim3(256), dim3(512), args, 0u,
                             stream);
}

// Round 9
// 25757.309 us; speedup vs baseline: 1.0036x; 1.0036x over previous
//
#include <hip/hip_runtime.h>

// HighwayLayerDiscrete: 256-step recurrent highway net, batch 64, units 1024.
// Reference per step: p0 h=lrelu(y@w_y+xe@w_x+b_in); p1/p2 h=lrelu(h@w_h+b_h);
// p3 y += h@w_out + b_out; out[:,t,:]=y.
//
// R16 = R15 RESUBMITTED VERBATIM (R15 never ran: container died before the
// first message -- same infra failure as R3; R14 on this container ran to
// completion, so no lingering-hang suspicion, and all polls are bounded).
// R15 = R14's 3-phase z-state algebra (NUMERICALLY VALIDATED in R14: passed)
// with the register cap unclamped. R14 post-mortem: __launch_bounds__(512,2)
// caps VGPR at 128 (2 waves/SIMD x 2048-reg pool); phase C's dual-pass
// pushed demand past it -> scratch spill -> 113 GB HBM traffic/dispatch
// (FETCH 3.8e7 KB, WRITE 7.3e7 KB) = the whole 25.8 ms. Fixes:
//  1. __launch_bounds__(512) (no min-waves): cap 256. Grid = 256 WGs on 256
//     CUs = 1 WG/CU always, so the min-occupancy arg bought NOTHING.
//     8 waves x <=256 VGPR still co-resident (pool 2048/SIMD).
//  2. acc[] REUSED for the z-pass (was separate accz[]): -16 live VGPRs.
// Algebra (R14): track z_t := y_t @ w_y as private state.
//   z_{t+1} = z_t + h2@w_ow + b_ow  (w_ow = w_out@w_y, b_ow = b_out@w_y,
//                                    precomputed in prologue GEMM k_wcat)
//   h0_{t+1} = lrelu(z_{t+1} + xp[t+1])  -- ELEMENTWISE, WG-private
//   y_{t+1} = y_t + h2@w_out + b_out     -- y = 1 reg/thread, never staged
// Pipeline/step (3 exchanges, was 4): A: h1=lrelu(h0@wh0+bh0);
//   B: h2=lrelu(h1@wh1+bh1); C: pass1 y+=h2@w_out+b_out (out[t]=y),
//   pass2 z+=h2@w_ow+b_ow, store h0'=lrelu(z+xp[t+1]).
// Carried R13 wins: per-producer flag stores + coalesced 32-lane poll
// (bounded); finalize operands prefetched; out-store deferred past flag post.
// Carried invariants: 256 coop blocks x 512 thr (R4); no cross-WG split-K
// (R2/R3); no fences (R1); sc1/LLC only (R9: sc0 deadlocks); release =
// waitcnt0+barrier+flag store; acquire = poll+barrier+clobber; LDS skew
// injective (R5); red2 de-aliased.

constexpr int B = 64, T = 256, U = 1024, E = 512;
constexpr int BU = B * U;     // 65536
constexpr int APITCH = 1156;  // A-row pitch (1024 + 36-skew; ==4 mod 8)

#define LRELU(v) ((v) > 0.f ? (v) : 0.2f * (v))

using f4 = float __attribute__((ext_vector_type(4)));

__device__ __forceinline__ unsigned long long llc_load64(const float* p) {
  return __hip_atomic_load((const unsigned long long*)p, __ATOMIC_RELAXED,
                           __HIP_MEMORY_SCOPE_AGENT);
}
__device__ __forceinline__ void llc_store(float* p, float v) {
  __hip_atomic_store(p, v, __ATOMIC_RELAXED, __HIP_MEMORY_SCOPE_AGENT);
}
__device__ __forceinline__ unsigned llc_flag(const unsigned* p) {
  return __hip_atomic_load(p, __ATOMIC_RELAXED, __HIP_MEMORY_SCOPE_AGENT);
}
__device__ __forceinline__ void llc_flag_store(unsigned* p, unsigned v) {
  __hip_atomic_store(p, v, __ATOMIC_RELAXED, __HIP_MEMORY_SCOPE_AGENT);
}

// -------- init: zero flags and the k_vecs atomic accumulators --------
__global__ void k_init(unsigned* __restrict__ flags, float* __restrict__ z0,
                       float* __restrict__ b_ow) {
  int i = blockIdx.x * 256 + threadIdx.x;  // grid 4 -> 1024
  if (i < 1024) {
    flags[i] = 0u;
    z0[i] = 0.f;
    b_ow[i] = 0.f;
  }
}

// ------- xproj[t*64+n][u] = emb[x[n][t]] @ w_x + b_in (R2/R3-proven) -------
__global__ __launch_bounds__(256) void k_xproj(
    const int* __restrict__ x, const float* __restrict__ emb,
    const float* __restrict__ w_x, const float* __restrict__ b_in,
    float* __restrict__ xp) {
  __shared__ float a_s[64][36];
  __shared__ float w_s[32][64];
  __shared__ int idxs[64];
  const int tid = threadIdx.x;
  const int m0 = blockIdx.x * 64;
  const int c0 = blockIdx.y * 64;
  if (tid < 64) {
    int m = m0 + tid;
    idxs[tid] = x[(m & 63) * T + (m >> 6)];  // x[n][t], row m = t*64+n
  }
  __syncthreads();
  const int rq = tid >> 4, cq = tid & 15;
  float acc[4][4] = {};
  for (int k0 = 0; k0 < E; k0 += 32) {
#pragma unroll
    for (int rep = 0; rep < 8; ++rep) {
      int e = rep * 256 + tid;
      int r = e >> 5, k = e & 31;
      a_s[r][k] = emb[(size_t)idxs[r] * E + k0 + k];
    }
#pragma unroll
    for (int rep = 0; rep < 2; ++rep) {
      int e = rep * 256 + tid;
      int kr = e >> 4, q = e & 15;
      *(float4*)&w_s[kr][4 * q] =
          *(const float4*)(w_x + (size_t)(k0 + kr) * U + c0 + 4 * q);
    }
    __syncthreads();
#pragma unroll
    for (int kc = 0; kc < 32; kc += 4) {
      float4 a4[4], w4[4];
#pragma unroll
      for (int i = 0; i < 4; ++i) a4[i] = *(const float4*)&a_s[4 * rq + i][kc];
#pragma unroll
      for (int kk = 0; kk < 4; ++kk)
        w4[kk] = *(const float4*)&w_s[kc + kk][4 * cq];
#pragma unroll
      for (int i = 0; i < 4; ++i) {
        const float av[4] = {a4[i].x, a4[i].y, a4[i].z, a4[i].w};
#pragma unroll
        for (int kk = 0; kk < 4; ++kk) {
          acc[i][0] += av[kk] * w4[kk].x;
          acc[i][1] += av[kk] * w4[kk].y;
          acc[i][2] += av[kk] * w4[kk].z;
          acc[i][3] += av[kk] * w4[kk].w;
        }
      }
    }
    __syncthreads();
  }
  const float4 bb = *(const float4*)(b_in + c0 + 4 * cq);
  const float bv[4] = {bb.x, bb.y, bb.z, bb.w};
#pragma unroll
  for (int i = 0; i < 4; ++i) {
    float4 o;
    o.x = acc[i][0] + bv[0];
    o.y = acc[i][1] + bv[1];
    o.z = acc[i][2] + bv[2];
    o.w = acc[i][3] + bv[3];
    *(float4*)(xp + (size_t)(m0 + 4 * rq + i) * U + c0 + 4 * cq) = o;
  }
}

// -------- w_ow[k][u] = sum_j w_out[k][j] * w_y[j][u]  (same tile GEMM) -----
__global__ __launch_bounds__(256) void k_wcat(const float* __restrict__ wo,
                                              const float* __restrict__ wy,
                                              float* __restrict__ wow) {
  __shared__ float a_s[64][36];
  __shared__ float w_s[32][64];
  const int tid = threadIdx.x;
  const int m0 = blockIdx.x * 64;
  const int c0 = blockIdx.y * 64;
  const int rq = tid >> 4, cq = tid & 15;
  float acc[4][4] = {};
  for (int k0 = 0; k0 < U; k0 += 32) {
#pragma unroll
    for (int rep = 0; rep < 8; ++rep) {
      int e = rep * 256 + tid;
      int r = e >> 5, k = e & 31;
      a_s[r][k] = wo[(size_t)(m0 + r) * U + k0 + k];
    }
#pragma unroll
    for (int rep = 0; rep < 2; ++rep) {
      int e = rep * 256 + tid;
      int kr = e >> 4, q = e & 15;
      *(float4*)&w_s[kr][4 * q] =
          *(const float4*)(wy + (size_t)(k0 + kr) * U + c0 + 4 * q);
    }
    __syncthreads();
#pragma unroll
    for (int kc = 0; kc < 32; kc += 4) {
      float4 a4[4], w4[4];
#pragma unroll
      for (int i = 0; i < 4; ++i) a4[i] = *(const float4*)&a_s[4 * rq + i][kc];
#pragma unroll
      for (int kk = 0; kk < 4; ++kk)
        w4[kk] = *(const float4*)&w_s[kc + kk][4 * cq];
#pragma unroll
      for (int i = 0; i < 4; ++i) {
        const float av[4] = {a4[i].x, a4[i].y, a4[i].z, a4[i].w};
#pragma unroll
        for (int kk = 0; kk < 4; ++kk) {
          acc[i][0] += av[kk] * w4[kk].x;
          acc[i][1] += av[kk] * w4[kk].y;
          acc[i][2] += av[kk] * w4[kk].z;
          acc[i][3] += av[kk] * w4[kk].w;
        }
      }
    }
    __syncthreads();
  }
#pragma unroll
  for (int i = 0; i < 4; ++i) {
    float4 o = {acc[i][0], acc[i][1], acc[i][2], acc[i][3]};
    *(float4*)(wow + (size_t)(m0 + 4 * rq + i) * U + c0 + 4 * cq) = o;
  }
}

// -------- z0[u] = h0 @ w_y[:,u];  b_ow[u] = b_out @ w_y[:,u] --------
__global__ void k_vecs(const float* __restrict__ h0,
                       const float* __restrict__ b_out,
                       const float* __restrict__ w_y, float* __restrict__ z0,
                       float* __restrict__ b_ow) {
  const int u = (blockIdx.x & 3) * 256 + threadIdx.x;
  const int kb = blockIdx.x >> 2;  // 8 k-blocks x 128
  float a0 = 0.f, a1 = 0.f;
  for (int k = kb * 128; k < kb * 128 + 128; ++k) {
    float w = w_y[(size_t)k * U + u];
    a0 += h0[k] * w;
    a1 += b_out[k] * w;
  }
  atomicAdd(&z0[u], a0);
  atomicAdd(&b_ow[u], a1);
}

// -------- slot1[n][u] = h0_0 = lrelu(z0[u] + xp[0][n][u]) --------
__global__ void k_fill(const float* __restrict__ z0,
                       const float* __restrict__ xp,
                       float* __restrict__ slot1) {
  int i = blockIdx.x * 256 + threadIdx.x;  // grid 256 -> 65536
  float v = z0[i & (U - 1)] + xp[i];
  slot1[i] = LRELU(v);
}

// ---------------- sequential pipeline: 768 phases ----------------
// 256 WGs = 8 rg x 32 cg. Thread (s,ri,ci): K-slice [32s,32s+32), rows
// [4ri,4ri+4) of 8, cols [4ci,4ci+4) of 32. Partials -> red2[s][out] pitch
// 264 (de-aliased). Phase Q = 3t+ph: ph0 A(w_h0), ph1 B(w_h1), ph2 C(w_out
// pass1 -> y, w_ow pass2 -> z, private h0' store).
__global__ __launch_bounds__(512) void k_seq(
    const float* __restrict__ xp, const float* __restrict__ w_h,
    const float* __restrict__ b_h, const float* __restrict__ w_out,
    const float* __restrict__ w_ow, const float* __restrict__ b_out,
    const float* __restrict__ b_ow, const float* __restrict__ z0,
    const float* __restrict__ h0, float* __restrict__ out,
    float* __restrict__ slots, unsigned* __restrict__ flags) {
  __shared__ float a_s[8 * APITCH];   // 9248 floats
  __shared__ float red2[32 * 264];    // 8448 floats (de-aliased)
  const int tid = threadIdx.x;
  const int cg = blockIdx.x & 31, rg = blockIdx.x >> 5;
  const int l = tid & 63;
  const int ci = l & 7, ri = (l >> 3) & 1;
  const int s = (tid >> 6) * 4 + ((l >> 4) & 3);
  const int cb = 4 * ci, r0 = 4 * ri, k0 = 32 * s;
  unsigned* const myflag = &flags[rg * 32 + cg];
  const unsigned* const pollf = &flags[rg * 32 + (l & 31)];
  // finalize coordinates + loop-invariant operands (valid for all tid)
  const int frow = 8 * rg + (tid >> 5);
  const int fu = 32 * cg + (tid & 31);
  const size_t fyi = (size_t)frow * U + fu;
  const float bh0r = b_h[fu], bh1r = b_h[U + fu];
  const float bor = b_out[fu], bowr = b_ow[fu];
  float y_reg = h0[fu];  // y_0 = broadcast(h0)
  float z_reg = z0[fu];  // z_0 = broadcast(h0 @ w_y)

  // W panel base for phase type 0/1/2 (C pass1 = w_out; pass2 loaded inline)
  auto wbase = [&](int pht) -> const float* {
    const float* Wsrc = (pht == 0)   ? w_h
                        : (pht == 1) ? (w_h + (size_t)U * U)
                                     : w_out;
    return Wsrc + (size_t)k0 * U + 32 * cg + cb;
  };
  f4 wreg[32];
  {
    const float* wp = wbase(0);
#pragma unroll
    for (int j = 0; j < 32; ++j) wreg[j] = *(const f4*)(wp + (size_t)j * U);
  }

  int t = 0, ph = 0;
  for (int Q = 0; Q < 3 * T; ++Q) {
    const float* Asrc =
        slots + (size_t)((Q + 1) & 1) * BU + (size_t)(8 * rg) * U;
    float* slotw = slots + (size_t)(Q & 1) * BU;
    // ---- 0. xp prefetch for C (next timestep's xproj; hides under poll) ---
    float xpre = 0.f;
    if (ph == 2 && tid < 256) {
      const int tn = (t < T - 1) ? t + 1 : t;  // clamped; unused at t=T-1
      xpre = xp[((size_t)tn * B + frow) * U + fu];
    }
    // ---- 1. acquire: wave0's 32 lanes, one 128B flag read, bounded ----
    if (Q > 0) {
      if (tid < 64) {
        const unsigned tg = (unsigned)Q;
        for (int it = 0; it < (1 << 20); ++it) {
          unsigned f = llc_flag(pollf);
          if (__all((int)(f >= tg))) break;
          __builtin_amdgcn_s_sleep(1);
        }
      }
      __syncthreads();
      asm volatile("" ::: "memory");
    }
    // ---- 2. stage A: 8 rows x 1024, 8B sc1 loads -> b128 LDS write ----
#pragma unroll
    for (int rep = 0; rep < 4; ++rep) {
      int idx4 = 512 * rep + tid;
      int row = idx4 >> 8, kq = idx4 & 255, k = 4 * kq;
      const float* pa = Asrc + (size_t)row * U + k;
      unsigned long long v0 = llc_load64(pa);
      unsigned long long v1 = llc_load64(pa + 2);
      f4 v;
      ((unsigned long long*)&v)[0] = v0;
      ((unsigned long long*)&v)[1] = v1;
      *(f4*)&a_s[row * APITCH + 36 * (k >> 5) + (k & 31)] = v;
    }
    __syncthreads();
    // ---- 3. pass-1 GEMM: A from LDS, W from registers ----
    f4 acc[4];
#pragma unroll
    for (int i = 0; i < 4; ++i) acc[i] = (f4){0.f, 0.f, 0.f, 0.f};
    const int abase = r0 * APITCH + 36 * s;
#pragma unroll
    for (int q = 0; q < 8; ++q) {
      const int ai = abase + 4 * q;
      f4 a0 = *(const f4*)&a_s[ai];
      f4 a1 = *(const f4*)&a_s[ai + APITCH];
      f4 a2 = *(const f4*)&a_s[ai + 2 * APITCH];
      f4 a3 = *(const f4*)&a_s[ai + 3 * APITCH];
      const f4 w0 = wreg[4 * q], w1 = wreg[4 * q + 1];
      const f4 w2 = wreg[4 * q + 2], w3 = wreg[4 * q + 3];
      acc[0] += a0.x * w0 + a0.y * w1 + a0.z * w2 + a0.w * w3;
      acc[1] += a1.x * w0 + a1.y * w1 + a1.z * w2 + a1.w * w3;
      acc[2] += a2.x * w0 + a2.y * w1 + a2.z * w2 + a2.w * w3;
      acc[3] += a3.x * w0 + a3.y * w1 + a3.z * w2 + a3.w * w3;
    }
    if (ph == 2) {
      // mid-C reload: w_ow panel for pass-2 (latency hides under red/finalize)
      const float* wp = w_ow + (size_t)k0 * U + 32 * cg + cb;
#pragma unroll
      for (int j = 0; j < 32; ++j) wreg[j] = *(const f4*)(wp + (size_t)j * U);
    }
    // ---- 4. write partials (de-aliased: no pre-barrier) ----
#pragma unroll
    for (int i = 0; i < 4; ++i)
      *(f4*)&red2[s * 264 + (r0 + i) * 32 + cb] = acc[i];
    __syncthreads();
    // ---- 5. finalize ----
    if (ph < 2) {
      if (tid < 256) {
        float sum = 0.f;
#pragma unroll
        for (int z = 0; z < 32; ++z) sum += red2[z * 264 + tid];
        float v = sum + (ph ? bh1r : bh0r);
        llc_store(slotw + fyi, LRELU(v));
      }
    } else {
      // C: finalize-y (private), then pass-2 GEMM with w_ow, finalize-z.
      // acc[] is REUSED for the z-pass (R14 spill fix: -16 live VGPRs).
      if (tid < 256) {
        float ysum = 0.f;
#pragma unroll
        for (int z = 0; z < 32; ++z) ysum += red2[z * 264 + tid];
        y_reg += ysum + bor;  // out-store deferred past flag post
      }
      __syncthreads();  // red2-y reads done -> safe to overwrite
#pragma unroll
      for (int i = 0; i < 4; ++i) acc[i] = (f4){0.f, 0.f, 0.f, 0.f};
#pragma unroll
      for (int q = 0; q < 8; ++q) {
        const int ai = abase + 4 * q;
        f4 a0 = *(const f4*)&a_s[ai];
        f4 a1 = *(const f4*)&a_s[ai + APITCH];
        f4 a2 = *(const f4*)&a_s[ai + 2 * APITCH];
        f4 a3 = *(const f4*)&a_s[ai + 3 * APITCH];
        const f4 w0 = wreg[4 * q], w1 = wreg[4 * q + 1];
        const f4 w2 = wreg[4 * q + 2], w3 = wreg[4 * q + 3];
        acc[0] += a0.x * w0 + a0.y * w1 + a0.z * w2 + a0.w * w3;
        acc[1] += a1.x * w0 + a1.y * w1 + a1.z * w2 + a1.w * w3;
        acc[2] += a2.x * w0 + a2.y * w1 + a2.z * w2 + a2.w * w3;
        acc[3] += a3.x * w0 + a3.y * w1 + a3.z * w2 + a3.w * w3;
      }
#pragma unroll
      for (int i = 0; i < 4; ++i)
        *(f4*)&red2[s * 264 + (r0 + i) * 32 + cb] = acc[i];
      __syncthreads();
      if (tid < 256) {
        float zsum = 0.f;
#pragma unroll
        for (int z = 0; z < 32; ++z) zsum += red2[z * 264 + tid];
        z_reg += zsum + bowr;
        if (t < T - 1) {  // h0' for the next timestep's phase A
          float v = z_reg + xpre;
          llc_store(slotw + fyi, LRELU(v));
        }
      }
    }
    // ---- 6. drain: exchange stores at LLC before the flag post ----
    asm volatile("" ::: "memory");
    __builtin_amdgcn_s_waitcnt(0);
    __syncthreads();
    // ---- 7. W prefetch for Q+1 (overlaps post + poll + next stage) ----
    if (Q < 3 * T - 1) {
      const float* wp = wbase(ph == 2 ? 0 : ph + 1);
#pragma unroll
      for (int j = 0; j < 32; ++j) wreg[j] = *(const f4*)(wp + (size_t)j * U);
    }
    // ---- 8. release: per-producer flag store ----
    if (tid == 0) llc_flag_store(myflag, (unsigned)(Q + 1));
    // ---- 9. deferred out-store (off the flag critical path) ----
    if (ph == 2 && tid < 256) out[((size_t)frow * T + t) * U + fu] = y_reg;
    if (++ph == 3) {
      ph = 0;
      ++t;
    }
  }
}

extern "C" void kernel_launch(void* const* d_in, const int* in_sizes, int n_in,
                              void* d_out, int out_size, void* d_ws,
                              size_t ws_size, hipStream_t stream) {
  const int* x = (const int*)d_in[0];
  const float* emb = (const float*)d_in[1];
  const float* w_y = (const float*)d_in[2];
  const float* w_x = (const float*)d_in[3];
  const float* b_in = (const float*)d_in[4];
  const float* w_h = (const float*)d_in[5];
  const float* b_h = (const float*)d_in[6];
  const float* w_out = (const float*)d_in[7];
  const float* b_out = (const float*)d_in[8];
  const float* h0 = (const float*)d_in[9];
  float* out = (float*)d_out;

  // workspace (floats): xproj | slots[2] | flags(1024u) | z0 | b_ow | w_ow
  float* ws = (float*)d_ws;
  float* xpb = ws;                           // T*B*U = 16,777,216
  float* slots = xpb + (size_t)T * B * U;    // 2*BU = 131,072
  unsigned* flags = (unsigned*)(slots + 2 * (size_t)BU);  // 1024 uints
  float* z0 = (float*)(flags + 1024);        // 1024
  float* b_ow = z0 + 1024;                   // 1024
  float* w_ow = b_ow + 1024;                 // U*U = 1,048,576 (4 MB)

  k_init<<<4, 256, 0, stream>>>(flags, z0, b_ow);
  dim3 g1(256, 16);
  k_xproj<<<g1, 256, 0, stream>>>(x, emb, w_x, b_in, xpb);
  dim3 g2(16, 16);
  k_wcat<<<g2, 256, 0, stream>>>(w_out, w_y, w_ow);
  k_vecs<<<32, 256, 0, stream>>>(h0, b_out, w_y, z0, b_ow);
  k_fill<<<256, 256, 0, stream>>>(z0, xpb, slots + (size_t)BU);

  void* args[] = {&xpb, &w_h, &b_h,  &w_out, &w_ow,  &b_out,
                  &b_ow, &z0,  &h0,   &out,   &slots, &flags};
  hipLaunchCooperativeKernel((void*)k_seq, dim3(256), dim3(512), args, 0u,
                             stream);
}

// Round 10
// 6985.115 us; speedup vs baseline: 3.7007x; 3.6875x over previous
//
#include <hip/hip_runtime.h>

// HighwayLayerDiscrete: 256-step recurrent highway net, batch 64, units 1024.
// Reference per step: p0 h=lrelu(y@w_y+xe@w_x+b_in); p1/p2 h=lrelu(h@w_h+b_h);
// p3 y += h@w_out + b_out; out[:,t,:]=y.
//
// R17 = 3-phase z-state algebra (numerically validated R14/R16: passed) with
// R13's EXACT register discipline. R16 post-mortem: VGPR stayed 128 with
// FETCH/WRITE ~113 GB regardless of launch_bounds -> the spill was DEMAND,
// not cap: two wreg reload sites (mid-C + step-7) forced the compiler to
// materialize wreg[32] (128 VGPRs) + 128 in-flight loads -> >256 demand ->
// whole-array scratch spill. Fix: ONE wreg use + ONE reload per phase
// (step-7 only, R13's proven pattern, 104 VGPR); phase C's second GEMM
// (w_ow) reads W INLINE from L2 inside the loop -- the exact pattern the
// compiler schedules at 104 VGPR in R7/R13. w_ow panel = 128 KB/WG,
// L2-resident (8 rgs share each panel; read every 3rd phase).
// Algebra: track z_t := y_t @ w_y as private state.
//   z_{t+1} = z_t + h2@w_ow + b_ow  (w_ow = w_out@w_y, b_ow = b_out@w_y,
//                                    precomputed in prologue GEMM k_wcat)
//   h0_{t+1} = lrelu(z_{t+1} + xp[t+1])  -- ELEMENTWISE, WG-private
//   y_{t+1} = y_t + h2@w_out + b_out     -- y = 1 reg/thread, never staged
// Pipeline/step (3 exchanges, was 4): A: h1=lrelu(h0@wh0+bh0);
//   B: h2=lrelu(h1@wh1+bh1); C: pass1 y+=h2@w_out+b_out (out[t]=y),
//   pass2 z+=h2@w_ow+b_ow (inline W), store h0'=lrelu(z+xp[t+1]).
// Carried R13 wins: per-producer flag stores + coalesced 32-lane poll
// (bounded); finalize operands prefetched; out-store deferred past flag post.
// Carried invariants: 256 coop blocks x 512 thr (R4); no cross-WG split-K
// (R2/R3); no fences (R1); sc1/LLC only (R9: sc0 deadlocks); release =
// waitcnt0+barrier+flag store; acquire = poll+barrier+clobber; LDS skew
// injective (R5); red2 de-aliased; launch_bounds (512,2) = R13's proven
// codegen context.

constexpr int B = 64, T = 256, U = 1024, E = 512;
constexpr int BU = B * U;     // 65536
constexpr int APITCH = 1156;  // A-row pitch (1024 + 36-skew; ==4 mod 8)

#define LRELU(v) ((v) > 0.f ? (v) : 0.2f * (v))

using f4 = float __attribute__((ext_vector_type(4)));

__device__ __forceinline__ unsigned long long llc_load64(const float* p) {
  return __hip_atomic_load((const unsigned long long*)p, __ATOMIC_RELAXED,
                           __HIP_MEMORY_SCOPE_AGENT);
}
__device__ __forceinline__ void llc_store(float* p, float v) {
  __hip_atomic_store(p, v, __ATOMIC_RELAXED, __HIP_MEMORY_SCOPE_AGENT);
}
__device__ __forceinline__ unsigned llc_flag(const unsigned* p) {
  return __hip_atomic_load(p, __ATOMIC_RELAXED, __HIP_MEMORY_SCOPE_AGENT);
}
__device__ __forceinline__ void llc_flag_store(unsigned* p, unsigned v) {
  __hip_atomic_store(p, v, __ATOMIC_RELAXED, __HIP_MEMORY_SCOPE_AGENT);
}

// -------- init: zero flags and the k_vecs atomic accumulators --------
__global__ void k_init(unsigned* __restrict__ flags, float* __restrict__ z0,
                       float* __restrict__ b_ow) {
  int i = blockIdx.x * 256 + threadIdx.x;  // grid 4 -> 1024
  if (i < 1024) {
    flags[i] = 0u;
    z0[i] = 0.f;
    b_ow[i] = 0.f;
  }
}

// ------- xproj[t*64+n][u] = emb[x[n][t]] @ w_x + b_in (R2/R3-proven) -------
__global__ __launch_bounds__(256) void k_xproj(
    const int* __restrict__ x, const float* __restrict__ emb,
    const float* __restrict__ w_x, const float* __restrict__ b_in,
    float* __restrict__ xp) {
  __shared__ float a_s[64][36];
  __shared__ float w_s[32][64];
  __shared__ int idxs[64];
  const int tid = threadIdx.x;
  const int m0 = blockIdx.x * 64;
  const int c0 = blockIdx.y * 64;
  if (tid < 64) {
    int m = m0 + tid;
    idxs[tid] = x[(m & 63) * T + (m >> 6)];  // x[n][t], row m = t*64+n
  }
  __syncthreads();
  const int rq = tid >> 4, cq = tid & 15;
  float acc[4][4] = {};
  for (int k0 = 0; k0 < E; k0 += 32) {
#pragma unroll
    for (int rep = 0; rep < 8; ++rep) {
      int e = rep * 256 + tid;
      int r = e >> 5, k = e & 31;
      a_s[r][k] = emb[(size_t)idxs[r] * E + k0 + k];
    }
#pragma unroll
    for (int rep = 0; rep < 2; ++rep) {
      int e = rep * 256 + tid;
      int kr = e >> 4, q = e & 15;
      *(float4*)&w_s[kr][4 * q] =
          *(const float4*)(w_x + (size_t)(k0 + kr) * U + c0 + 4 * q);
    }
    __syncthreads();
#pragma unroll
    for (int kc = 0; kc < 32; kc += 4) {
      float4 a4[4], w4[4];
#pragma unroll
      for (int i = 0; i < 4; ++i) a4[i] = *(const float4*)&a_s[4 * rq + i][kc];
#pragma unroll
      for (int kk = 0; kk < 4; ++kk)
        w4[kk] = *(const float4*)&w_s[kc + kk][4 * cq];
#pragma unroll
      for (int i = 0; i < 4; ++i) {
        const float av[4] = {a4[i].x, a4[i].y, a4[i].z, a4[i].w};
#pragma unroll
        for (int kk = 0; kk < 4; ++kk) {
          acc[i][0] += av[kk] * w4[kk].x;
          acc[i][1] += av[kk] * w4[kk].y;
          acc[i][2] += av[kk] * w4[kk].z;
          acc[i][3] += av[kk] * w4[kk].w;
        }
      }
    }
    __syncthreads();
  }
  const float4 bb = *(const float4*)(b_in + c0 + 4 * cq);
  const float bv[4] = {bb.x, bb.y, bb.z, bb.w};
#pragma unroll
  for (int i = 0; i < 4; ++i) {
    float4 o;
    o.x = acc[i][0] + bv[0];
    o.y = acc[i][1] + bv[1];
    o.z = acc[i][2] + bv[2];
    o.w = acc[i][3] + bv[3];
    *(float4*)(xp + (size_t)(m0 + 4 * rq + i) * U + c0 + 4 * cq) = o;
  }
}

// -------- w_ow[k][u] = sum_j w_out[k][j] * w_y[j][u]  (same tile GEMM) -----
__global__ __launch_bounds__(256) void k_wcat(const float* __restrict__ wo,
                                              const float* __restrict__ wy,
                                              float* __restrict__ wow) {
  __shared__ float a_s[64][36];
  __shared__ float w_s[32][64];
  const int tid = threadIdx.x;
  const int m0 = blockIdx.x * 64;
  const int c0 = blockIdx.y * 64;
  const int rq = tid >> 4, cq = tid & 15;
  float acc[4][4] = {};
  for (int k0 = 0; k0 < U; k0 += 32) {
#pragma unroll
    for (int rep = 0; rep < 8; ++rep) {
      int e = rep * 256 + tid;
      int r = e >> 5, k = e & 31;
      a_s[r][k] = wo[(size_t)(m0 + r) * U + k0 + k];
    }
#pragma unroll
    for (int rep = 0; rep < 2; ++rep) {
      int e = rep * 256 + tid;
      int kr = e >> 4, q = e & 15;
      *(float4*)&w_s[kr][4 * q] =
          *(const float4*)(wy + (size_t)(k0 + kr) * U + c0 + 4 * q);
    }
    __syncthreads();
#pragma unroll
    for (int kc = 0; kc < 32; kc += 4) {
      float4 a4[4], w4[4];
#pragma unroll
      for (int i = 0; i < 4; ++i) a4[i] = *(const float4*)&a_s[4 * rq + i][kc];
#pragma unroll
      for (int kk = 0; kk < 4; ++kk)
        w4[kk] = *(const float4*)&w_s[kc + kk][4 * cq];
#pragma unroll
      for (int i = 0; i < 4; ++i) {
        const float av[4] = {a4[i].x, a4[i].y, a4[i].z, a4[i].w};
#pragma unroll
        for (int kk = 0; kk < 4; ++kk) {
          acc[i][0] += av[kk] * w4[kk].x;
          acc[i][1] += av[kk] * w4[kk].y;
          acc[i][2] += av[kk] * w4[kk].z;
          acc[i][3] += av[kk] * w4[kk].w;
        }
      }
    }
    __syncthreads();
  }
#pragma unroll
  for (int i = 0; i < 4; ++i) {
    float4 o = {acc[i][0], acc[i][1], acc[i][2], acc[i][3]};
    *(float4*)(wow + (size_t)(m0 + 4 * rq + i) * U + c0 + 4 * cq) = o;
  }
}

// -------- z0[u] = h0 @ w_y[:,u];  b_ow[u] = b_out @ w_y[:,u] --------
__global__ void k_vecs(const float* __restrict__ h0,
                       const float* __restrict__ b_out,
                       const float* __restrict__ w_y, float* __restrict__ z0,
                       float* __restrict__ b_ow) {
  const int u = (blockIdx.x & 3) * 256 + threadIdx.x;
  const int kb = blockIdx.x >> 2;  // 8 k-blocks x 128
  float a0 = 0.f, a1 = 0.f;
  for (int k = kb * 128; k < kb * 128 + 128; ++k) {
    float w = w_y[(size_t)k * U + u];
    a0 += h0[k] * w;
    a1 += b_out[k] * w;
  }
  atomicAdd(&z0[u], a0);
  atomicAdd(&b_ow[u], a1);
}

// -------- slot1[n][u] = h0_0 = lrelu(z0[u] + xp[0][n][u]) --------
__global__ void k_fill(const float* __restrict__ z0,
                       const float* __restrict__ xp,
                       float* __restrict__ slot1) {
  int i = blockIdx.x * 256 + threadIdx.x;  // grid 256 -> 65536
  float v = z0[i & (U - 1)] + xp[i];
  slot1[i] = LRELU(v);
}

// ---------------- sequential pipeline: 768 phases ----------------
// 256 WGs = 8 rg x 32 cg. Thread (s,ri,ci): K-slice [32s,32s+32), rows
// [4ri,4ri+4) of 8, cols [4ci,4ci+4) of 32. Partials -> red2[s][out] pitch
// 264 (de-aliased). Phase Q = 3t+ph: ph0 A(w_h0), ph1 B(w_h1), ph2 C
// (pass1 w_out from wreg -> y; pass2 w_ow INLINE from L2 -> z; h0' store).
__global__ __launch_bounds__(512, 2) void k_seq(
    const float* __restrict__ xp, const float* __restrict__ w_h,
    const float* __restrict__ b_h, const float* __restrict__ w_out,
    const float* __restrict__ w_ow, const float* __restrict__ b_out,
    const float* __restrict__ b_ow, const float* __restrict__ z0,
    const float* __restrict__ h0, float* __restrict__ out,
    float* __restrict__ slots, unsigned* __restrict__ flags) {
  __shared__ float a_s[8 * APITCH];  // 9248 floats
  __shared__ float red2[32 * 264];   // 8448 floats (de-aliased)
  const int tid = threadIdx.x;
  const int cg = blockIdx.x & 31, rg = blockIdx.x >> 5;
  const int l = tid & 63;
  const int ci = l & 7, ri = (l >> 3) & 1;
  const int s = (tid >> 6) * 4 + ((l >> 4) & 3);
  const int cb = 4 * ci, r0 = 4 * ri, k0 = 32 * s;
  unsigned* const myflag = &flags[rg * 32 + cg];
  const unsigned* const pollf = &flags[rg * 32 + (l & 31)];
  // finalize coordinates + loop-invariant operands (valid for all tid)
  const int frow = 8 * rg + (tid >> 5);
  const int fu = 32 * cg + (tid & 31);
  const size_t fyi = (size_t)frow * U + fu;
  const float bh0r = b_h[fu], bh1r = b_h[U + fu];
  const float bor = b_out[fu], bowr = b_ow[fu];
  float y_reg = h0[fu];  // y_0 = broadcast(h0)
  float z_reg = z0[fu];  // z_0 = broadcast(h0 @ w_y)
  // pass-2 W pointer (loop-invariant)
  const float* const wp2 = w_ow + (size_t)k0 * U + 32 * cg + cb;

  // W panel base for phase type 0/1/2 (pass-1 source only)
  auto wbase = [&](int pht) -> const float* {
    const float* Wsrc = (pht == 0)   ? w_h
                        : (pht == 1) ? (w_h + (size_t)U * U)
                                     : w_out;
    return Wsrc + (size_t)k0 * U + 32 * cg + cb;
  };
  f4 wreg[32];
  {
    const float* wp = wbase(0);
#pragma unroll
    for (int j = 0; j < 32; ++j) wreg[j] = *(const f4*)(wp + (size_t)j * U);
  }

  int t = 0, ph = 0;
  for (int Q = 0; Q < 3 * T; ++Q) {
    const float* Asrc =
        slots + (size_t)((Q + 1) & 1) * BU + (size_t)(8 * rg) * U;
    float* slotw = slots + (size_t)(Q & 1) * BU;
    // ---- 0. xp prefetch for C (next timestep's xproj; hides under poll) ---
    float xpre = 0.f;
    if (ph == 2 && tid < 256) {
      const int tn = (t < T - 1) ? t + 1 : t;  // clamped; unused at t=T-1
      xpre = xp[((size_t)tn * B + frow) * U + fu];
    }
    // ---- 1. acquire: wave0's 32 lanes, one 128B flag read, bounded ----
    if (Q > 0) {
      if (tid < 64) {
        const unsigned tg = (unsigned)Q;
        for (int it = 0; it < (1 << 20); ++it) {
          unsigned f = llc_flag(pollf);
          if (__all((int)(f >= tg))) break;
          __builtin_amdgcn_s_sleep(1);
        }
      }
      __syncthreads();
      asm volatile("" ::: "memory");
    }
    // ---- 2. stage A: 8 rows x 1024, 8B sc1 loads -> b128 LDS write ----
#pragma unroll
    for (int rep = 0; rep < 4; ++rep) {
      int idx4 = 512 * rep + tid;
      int row = idx4 >> 8, kq = idx4 & 255, k = 4 * kq;
      const float* pa = Asrc + (size_t)row * U + k;
      unsigned long long v0 = llc_load64(pa);
      unsigned long long v1 = llc_load64(pa + 2);
      f4 v;
      ((unsigned long long*)&v)[0] = v0;
      ((unsigned long long*)&v)[1] = v1;
      *(f4*)&a_s[row * APITCH + 36 * (k >> 5) + (k & 31)] = v;
    }
    __syncthreads();
    // ---- 3. pass-1 GEMM: A from LDS, W from registers ----
    f4 acc[4];
#pragma unroll
    for (int i = 0; i < 4; ++i) acc[i] = (f4){0.f, 0.f, 0.f, 0.f};
    const int abase = r0 * APITCH + 36 * s;
#pragma unroll
    for (int q = 0; q < 8; ++q) {
      const int ai = abase + 4 * q;
      f4 a0 = *(const f4*)&a_s[ai];
      f4 a1 = *(const f4*)&a_s[ai + APITCH];
      f4 a2 = *(const f4*)&a_s[ai + 2 * APITCH];
      f4 a3 = *(const f4*)&a_s[ai + 3 * APITCH];
      const f4 w0 = wreg[4 * q], w1 = wreg[4 * q + 1];
      const f4 w2 = wreg[4 * q + 2], w3 = wreg[4 * q + 3];
      acc[0] += a0.x * w0 + a0.y * w1 + a0.z * w2 + a0.w * w3;
      acc[1] += a1.x * w0 + a1.y * w1 + a1.z * w2 + a1.w * w3;
      acc[2] += a2.x * w0 + a2.y * w1 + a2.z * w2 + a2.w * w3;
      acc[3] += a3.x * w0 + a3.y * w1 + a3.z * w2 + a3.w * w3;
    }
    // ---- 4. write partials (de-aliased: no pre-barrier) ----
#pragma unroll
    for (int i = 0; i < 4; ++i)
      *(f4*)&red2[s * 264 + (r0 + i) * 32 + cb] = acc[i];
    __syncthreads();
    // ---- 5. finalize ----
    if (ph < 2) {
      if (tid < 256) {
        float sum = 0.f;
#pragma unroll
        for (int z = 0; z < 32; ++z) sum += red2[z * 264 + tid];
        float v = sum + (ph ? bh1r : bh0r);
        llc_store(slotw + fyi, LRELU(v));
      }
    } else {
      // C: finalize-y (private), then pass-2 GEMM with INLINE w_ow loads
      // (single wreg reload site per phase = R13's 104-VGPR codegen).
      if (tid < 256) {
        float ysum = 0.f;
#pragma unroll
        for (int z = 0; z < 32; ++z) ysum += red2[z * 264 + tid];
        y_reg += ysum + bor;  // out-store deferred past flag post
      }
      __syncthreads();  // red2-y reads done -> safe to overwrite
#pragma unroll
      for (int i = 0; i < 4; ++i) acc[i] = (f4){0.f, 0.f, 0.f, 0.f};
#pragma unroll
      for (int q = 0; q < 8; ++q) {
        const int ai = abase + 4 * q;
        f4 a0 = *(const f4*)&a_s[ai];
        f4 a1 = *(const f4*)&a_s[ai + APITCH];
        f4 a2 = *(const f4*)&a_s[ai + 2 * APITCH];
        f4 a3 = *(const f4*)&a_s[ai + 3 * APITCH];
        const f4 w0 = *(const f4*)(wp2 + (size_t)(4 * q) * U);
        const f4 w1 = *(const f4*)(wp2 + (size_t)(4 * q + 1) * U);
        const f4 w2 = *(const f4*)(wp2 + (size_t)(4 * q + 2) * U);
        const f4 w3 = *(const f4*)(wp2 + (size_t)(4 * q + 3) * U);
        acc[0] += a0.x * w0 + a0.y * w1 + a0.z * w2 + a0.w * w3;
        acc[1] += a1.x * w0 + a1.y * w1 + a1.z * w2 + a1.w * w3;
        acc[2] += a2.x * w0 + a2.y * w1 + a2.z * w2 + a2.w * w3;
        acc[3] += a3.x * w0 + a3.y * w1 + a3.z * w2 + a3.w * w3;
      }
#pragma unroll
      for (int i = 0; i < 4; ++i)
        *(f4*)&red2[s * 264 + (r0 + i) * 32 + cb] = acc[i];
      __syncthreads();
      if (tid < 256) {
        float zsum = 0.f;
#pragma unroll
        for (int z = 0; z < 32; ++z) zsum += red2[z * 264 + tid];
        z_reg += zsum + bowr;
        if (t < T - 1) {  // h0' for the next timestep's phase A
          float v = z_reg + xpre;
          llc_store(slotw + fyi, LRELU(v));
        }
      }
    }
    // ---- 6. drain: exchange stores at LLC before the flag post ----
    asm volatile("" ::: "memory");
    __builtin_amdgcn_s_waitcnt(0);
    __syncthreads();
    // ---- 7. W prefetch for Q+1 (SINGLE reload site; overlaps post + poll
    //         + next stage -- R13's proven pattern) ----
    if (Q < 3 * T - 1) {
      const float* wp = wbase(ph == 2 ? 0 : ph + 1);
#pragma unroll
      for (int j = 0; j < 32; ++j) wreg[j] = *(const f4*)(wp + (size_t)j * U);
    }
    // ---- 8. release: per-producer flag store ----
    if (tid == 0) llc_flag_store(myflag, (unsigned)(Q + 1));
    // ---- 9. deferred out-store (off the flag critical path) ----
    if (ph == 2 && tid < 256) out[((size_t)frow * T + t) * U + fu] = y_reg;
    if (++ph == 3) {
      ph = 0;
      ++t;
    }
  }
}

extern "C" void kernel_launch(void* const* d_in, const int* in_sizes, int n_in,
                              void* d_out, int out_size, void* d_ws,
                              size_t ws_size, hipStream_t stream) {
  const int* x = (const int*)d_in[0];
  const float* emb = (const float*)d_in[1];
  const float* w_y = (const float*)d_in[2];
  const float* w_x = (const float*)d_in[3];
  const float* b_in = (const float*)d_in[4];
  const float* w_h = (const float*)d_in[5];
  const float* b_h = (const float*)d_in[6];
  const float* w_out = (const float*)d_in[7];
  const float* b_out = (const float*)d_in[8];
  const float* h0 = (const float*)d_in[9];
  float* out = (float*)d_out;

  // workspace (floats): xproj | slots[2] | flags(1024u) | z0 | b_ow | w_ow
  float* ws = (float*)d_ws;
  float* xpb = ws;                         // T*B*U = 16,777,216
  float* slots = xpb + (size_t)T * B * U;  // 2*BU = 131,072
  unsigned* flags = (unsigned*)(slots + 2 * (size_t)BU);  // 1024 uints
  float* z0 = (float*)(flags + 1024);      // 1024
  float* b_ow = z0 + 1024;                 // 1024
  float* w_ow = b_ow + 1024;               // U*U = 1,048,576 (4 MB)

  k_init<<<4, 256, 0, stream>>>(flags, z0, b_ow);
  dim3 g1(256, 16);
  k_xproj<<<g1, 256, 0, stream>>>(x, emb, w_x, b_in, xpb);
  dim3 g2(16, 16);
  k_wcat<<<g2, 256, 0, stream>>>(w_out, w_y, w_ow);
  k_vecs<<<32, 256, 0, stream>>>(h0, b_out, w_y, z0, b_ow);
  k_fill<<<256, 256, 0, stream>>>(z0, xpb, slots + (size_t)BU);

  void* args[] = {&xpb,  &w_h, &b_h, &w_out, &w_ow,  &b_out,
                  &b_ow, &z0,  &h0,  &out,   &slots, &flags};
  hipLaunchCooperativeKernel((void*)k_seq, dim3(256), dim3(512), args, 0u,
                             stream);
}